// Round 1
// baseline (194.884 us; speedup 1.0000x reference)
//
#include <hip/hip_runtime.h>

#define BLOCK 256
#define GRID 2048

__global__ __launch_bounds__(BLOCK) void asym_l1_partial(
    const float4* __restrict__ c4, const float4* __restrict__ t4,
    const float* __restrict__ penalty, float* __restrict__ partials, long n4) {
  __shared__ float pen[32];
  if (threadIdx.x < 32) pen[threadIdx.x] = penalty[threadIdx.x];
  __syncthreads();

  float acc = 0.0f;
  const long stride = (long)gridDim.x * blockDim.x;
  for (long i = (long)blockIdx.x * blockDim.x + threadIdx.x; i < n4; i += stride) {
    float4 cv = c4[i];
    float4 tv = t4[i];
    int col = (int)((i * 4) & 31);   // M=32, vec4-aligned -> col in {0,4,...,28}
    float d0 = cv.x - tv.x;
    float d1 = cv.y - tv.y;
    float d2 = cv.z - tv.z;
    float d3 = cv.w - tv.w;
    acc += (d0 < 0.0f) ? -pen[col + 0] * d0 : d0;
    acc += (d1 < 0.0f) ? -pen[col + 1] * d1 : d1;
    acc += (d2 < 0.0f) ? -pen[col + 2] * d2 : d2;
    acc += (d3 < 0.0f) ? -pen[col + 3] * d3 : d3;
  }

  // wave-64 reduce
  #pragma unroll
  for (int off = 32; off > 0; off >>= 1) acc += __shfl_down(acc, off, 64);

  __shared__ float wsum[BLOCK / 64];
  const int lane = threadIdx.x & 63;
  const int wid  = threadIdx.x >> 6;
  if (lane == 0) wsum[wid] = acc;
  __syncthreads();
  if (threadIdx.x == 0) {
    float s = 0.0f;
    #pragma unroll
    for (int w = 0; w < BLOCK / 64; ++w) s += wsum[w];
    partials[blockIdx.x] = s;
  }
}

__global__ __launch_bounds__(BLOCK) void asym_l1_final(
    const float* __restrict__ partials, float* __restrict__ out,
    int nparts, float inv_n) {
  float acc = 0.0f;
  for (int i = threadIdx.x; i < nparts; i += BLOCK) acc += partials[i];

  #pragma unroll
  for (int off = 32; off > 0; off >>= 1) acc += __shfl_down(acc, off, 64);

  __shared__ float wsum[BLOCK / 64];
  const int lane = threadIdx.x & 63;
  const int wid  = threadIdx.x >> 6;
  if (lane == 0) wsum[wid] = acc;
  __syncthreads();
  if (threadIdx.x == 0) {
    float s = 0.0f;
    #pragma unroll
    for (int w = 0; w < BLOCK / 64; ++w) s += wsum[w];
    out[0] = s * inv_n;
  }
}

extern "C" void kernel_launch(void* const* d_in, const int* in_sizes, int n_in,
                              void* d_out, int out_size, void* d_ws, size_t ws_size,
                              hipStream_t stream) {
  const float* computed = (const float*)d_in[0];
  const float* target   = (const float*)d_in[1];
  const float* penalty  = (const float*)d_in[2];
  float* out = (float*)d_out;
  float* partials = (float*)d_ws;   // GRID * 4 bytes = 8 KB scratch

  const long total = (long)in_sizes[0];        // N * M = 134217728
  const long n4    = total / 4;
  const long n_samples = total / (long)in_sizes[2];  // N (M = in_sizes[2] = 32)
  const float inv_n = 1.0f / (float)n_samples;

  asym_l1_partial<<<GRID, BLOCK, 0, stream>>>(
      (const float4*)computed, (const float4*)target, penalty, partials, n4);
  asym_l1_final<<<1, BLOCK, 0, stream>>>(partials, out, GRID, inv_n);
}